// Round 12
// baseline (146.560 us; speedup 1.0000x reference)
//
#include <hip/hip_runtime.h>

#define N_NODES 10000
#define DIM 512
#define NE 160000

typedef _Float16 f16;
typedef _Float16 f16x2 __attribute__((ext_vector_type(2)));
typedef _Float16 f16x8 __attribute__((ext_vector_type(8)));
typedef float f32x4 __attribute__((ext_vector_type(4)));

__device__ __forceinline__ void gload16(const void* g, void* l) {
  __builtin_amdgcn_global_load_lds((const __attribute__((address_space(1))) void*)g,
                                   (__attribute__((address_space(3))) void*)l, 16, 0, 0);
}

// ---------------- fused setup: zero deg + cast x + all weight prep ----------------
// blocks [0,40):        zero deg
// blocks [40,5040):     cast x -> x16 (1.28M float4 quads)
// blocks [5040,5552):   cast W2r/W2o -> w2cat
// blocks [5552,5808):   wd1_build -> bdt
// blocks [5808,5872):   dvec
// blocks [5872,6000):   wtrans W1r/W1o -> w1c

__global__ __launch_bounds__(256) void setup_kernel(
    const float* __restrict__ x, f16* __restrict__ x16, int* __restrict__ deg,
    const float* __restrict__ W1r, const float* __restrict__ W1o,
    const float* __restrict__ W2r, const float* __restrict__ W2o,
    const float* __restrict__ Wd1, const float* __restrict__ b2,
    const float* __restrict__ bd1, f16* __restrict__ w1c, f16* __restrict__ w2cat,
    f16* __restrict__ bdt, float* __restrict__ dvec) {
  int b = blockIdx.x, t = threadIdx.x;
  if (b < 40) {
    int i = b * 256 + t;
    if (i < N_NODES) deg[i] = 0;
    return;
  }
  b -= 40;
  if (b < 5000) {  // cast x
    int i = b * 256 + t;
    float4 v = ((const float4*)x)[i];
    f16 h0 = (f16)v.x, h1 = (f16)v.y, h2 = (f16)v.z, h3 = (f16)v.w;
    ushort4 hv = {*(ushort*)&h0, *(ushort*)&h1, *(ushort*)&h2, *(ushort*)&h3};
    ((ushort4*)x16)[i] = hv;
    return;
  }
  b -= 5000;
  if (b < 512) {  // cast W2r / W2o
    const float* s = (b < 256) ? W2r : W2o;
    f16* d = w2cat + (b < 256 ? 0 : (size_t)512 * 512);
    int i = (b & 255) * 256 + t;
    float4 v = ((const float4*)s)[i];
    f16 h0 = (f16)v.x, h1 = (f16)v.y, h2 = (f16)v.z, h3 = (f16)v.w;
    ushort4 hv = {*(ushort*)&h0, *(ushort*)&h1, *(ushort*)&h2, *(ushort*)&h3};
    ((ushort4*)d)[i] = hv;
    return;
  }
  b -= 512;
  if (b < 256) {  // wd1_build: bdt[j][k] = Wd1[(j<64?k:512+k)][j&63]
    int lin = b * 256 + t;
    int j = lin >> 9, k = lin & 511;
    bdt[lin] = (f16)Wd1[(size_t)(j < 64 ? k : 512 + k) * 64 + (j & 63)];
    return;
  }
  b -= 256;
  if (b < 64) {  // dvec[j] = bd1[j] + sum_k b2[k]*(Wd1[k][j]+Wd1[512+k][j])
    int j = b;
    float s = 0;
    for (int k = t; k < 512; k += 256) {
      float bk = b2[k];
      s += bk * (Wd1[(size_t)k * 64 + j] + Wd1[(size_t)(512 + k) * 64 + j]);
    }
#pragma unroll
    for (int off = 32; off >= 1; off >>= 1) s += __shfl_xor(s, off);
    __shared__ float red[4];
    int w = t >> 6, l = t & 63;
    if (l == 0) red[w] = s;
    __syncthreads();
    if (t == 0) dvec[j] = bd1[j] + red[0] + red[1] + red[2] + red[3];
    return;
  }
  b -= 64;
  {  // wtrans: W1r (b<64) / W1o (b>=64) -> w1c transposed fp16
    const float* src = (b < 64) ? W1r : W1o;
    f16* dh = w1c + (b < 64 ? 0 : (size_t)512 * 512);
    int tile = b & 63;
    __shared__ float sT[64][65];
    int tr = tile >> 3, tc = tile & 7;
    for (int i = 0; i < 16; ++i) {
      int lin = i * 256 + t;
      int r = lin >> 6, c = lin & 63;
      sT[r][c] = src[(size_t)(tr * 64 + r) * 512 + tc * 64 + c];
    }
    __syncthreads();
    for (int i = 0; i < 16; ++i) {
      int lin = i * 256 + t;
      int n = lin >> 6, k = lin & 63;
      dh[(size_t)(tc * 64 + n) * 512 + tr * 64 + k] = (f16)sT[k][n];
    }
  }
}

// ---------------- CSR construction ----------------

__global__ __launch_bounds__(256) void hist_kernel(const int* __restrict__ dst,
                                                   int* __restrict__ deg, int E) {
  int e = blockIdx.x * 256 + threadIdx.x;
  if (e < E) atomicAdd(&deg[dst[e]], 1);
}

__global__ __launch_bounds__(256) void scan_kernel(const int* __restrict__ deg,
                                                   int* __restrict__ rowptr,
                                                   int* __restrict__ cursor) {
  __shared__ int partial[256];
  const int CH = 40;
  int tid = threadIdx.x;
  int start = tid * CH;
  int sum = 0;
  for (int i = 0; i < CH; ++i) {
    int idx = start + i;
    if (idx < N_NODES) sum += deg[idx];
  }
  partial[tid] = sum;
  __syncthreads();
  if (tid == 0) {
    int run = 0;
    for (int i = 0; i < 256; ++i) { int t = partial[i]; partial[i] = run; run += t; }
  }
  __syncthreads();
  int off = partial[tid];
  for (int i = 0; i < CH; ++i) {
    int idx = start + i;
    if (idx < N_NODES) {
      rowptr[idx] = off;
      cursor[idx] = off;
      off += deg[idx];
    }
  }
  if (tid == 255) rowptr[N_NODES] = off;
}

__global__ __launch_bounds__(256) void scatter_kernel(const int* __restrict__ src,
                                                      const int* __restrict__ dst,
                                                      const float* __restrict__ ew,
                                                      int* __restrict__ cursor,
                                                      int* __restrict__ s_src,
                                                      float* __restrict__ s_ew, int E) {
  int e = blockIdx.x * 256 + threadIdx.x;
  if (e < E) {
    int d = dst[e];
    int p = atomicAdd(&cursor[d], 1);
    s_src[p] = src[e];
    s_ew[p] = ew[e];
  }
}

// ---------------- MFMA GEMM (dual-problem): out(f16) = A(f16) @ B(f16)^T ----------
// Blocks [0,n1) solve problem 1, blocks [n1,grid) solve problem 2.
// A: [M][512] fp16. B: [NB*BN][512] fp16. Block tile BM x BN, 4 waves 2x2, BK=32,
// K=512. Columns >= nsplit go to outB at (col-nsplit); stride ldo.
// XCD-chunked bijective block swizzle per segment (T1/m204).

template <int BM, int BN>
__global__ __launch_bounds__(256) void gemm_f16(
    const f16* __restrict__ A1, const f16* __restrict__ B1, f16* __restrict__ oA1,
    f16* __restrict__ oB1, int M1, int NB1, int ns1, int ldo1, int n1,
    const f16* __restrict__ A2, const f16* __restrict__ B2, f16* __restrict__ oA2,
    f16* __restrict__ oB2, int M2, int NB2, int ns2, int ldo2) {
  constexpr int ASLOTS = BM / 16;
  constexpr int SLOTS = (BM + BN) / 16;
  constexpr int SPW = SLOTS / 4;
  constexpr int MI = BM / 32;
  constexpr int NJ = BN / 32;
  __shared__ char smem[SLOTS * 1024];

  int lin = blockIdx.x;
  const f16 *A, *B;
  f16 *outA, *outB;
  int M, NB, nsplit, ldo, n;
  if (lin < n1) {
    A = A1; B = B1; outA = oA1; outB = oB1;
    M = M1; NB = NB1; nsplit = ns1; ldo = ldo1; n = n1;
  } else {
    lin -= n1;
    A = A2; B = B2; outA = oA2; outB = oB2;
    M = M2; NB = NB2; nsplit = ns2; ldo = ldo2; n = gridDim.x - n1;
  }

  // bijective XCD swizzle within segment; bn varies fastest
  int q = n >> 3, r = n & 7, xcd = lin & 7;
  int base = xcd < r ? xcd * (q + 1) : r * (q + 1) + (xcd - r) * q;
  int swz = base + (lin >> 3);
  int bm = (swz / NB) * BM;
  int bn = (swz % NB) * BN;

  int tid = threadIdx.x;
  int w = tid >> 6, l = tid & 63;
  int wr = w & 1, wc = w >> 1;

  f32x4 acc[MI][NJ] = {};

  int lr = l >> 2;        // row within 16-row slot
  int lc = (l & 3) * 8;   // fp16 offset within 32-wide stripe

  for (int k0 = 0; k0 < 512; k0 += 32) {
    __syncthreads();
#pragma unroll
    for (int i = 0; i < SPW; ++i) {
      int s = w * SPW + i;
      const f16* src;
      int grow;
      if (s < ASLOTS) {
        src = A; grow = bm + s * 16 + lr; if (grow > M - 1) grow = M - 1;
      } else {
        src = B; grow = bn + (s - ASLOTS) * 16 + lr;
      }
      gload16(src + (size_t)grow * 512 + k0 + lc, smem + s * 1024);
    }
    __syncthreads();

    int rsel = l & 15;
    int ksb = (l >> 4) * 16;  // byte offset of k-slice
    f16x8 fA[MI], fB[NJ];
#pragma unroll
    for (int i = 0; i < MI; ++i) {
      int ra = wr * (BM / 2) + i * 16 + rsel;
      fA[i] = *(const f16x8*)(smem + ra * 64 + ksb);
    }
#pragma unroll
    for (int j = 0; j < NJ; ++j) {
      int rb = wc * (BN / 2) + j * 16 + rsel;
      fB[j] = *(const f16x8*)(smem + ASLOTS * 1024 + rb * 64 + ksb);
    }
#pragma unroll
    for (int i = 0; i < MI; ++i)
#pragma unroll
      for (int j = 0; j < NJ; ++j)
        acc[i][j] = __builtin_amdgcn_mfma_f32_16x16x32_f16(fA[i], fB[j], acc[i][j], 0, 0, 0);
  }

  // epilogue: C/D layout col = lane&15, row = (lane>>4)*4 + reg
#pragma unroll
  for (int i = 0; i < MI; ++i) {
#pragma unroll
    for (int j = 0; j < NJ; ++j) {
      int col = bn + wc * (BN / 2) + j * 16 + (l & 15);
      f16* outp; int ocol;
      if (col < nsplit) { outp = outA; ocol = col; }
      else              { outp = outB; ocol = col - nsplit; }
#pragma unroll
      for (int rg = 0; rg < 4; ++rg) {
        int row = bm + wr * (BM / 2) + i * 16 + (l >> 4) * 4 + rg;
        if (row < M) outp[(size_t)row * ldo + ocol] = (f16)acc[i][j][rg];
      }
    }
  }
}

// ---------------- combine: z = relu(mean-gather(Yl) + Yr + bias) --------
// One block (4 waves) per node; edges interleaved across waves (tail-balanced);
// partial sums via LDS [4][8][64] (conflict-free); wave 0 reduces + writes.

__global__ __launch_bounds__(256) void combine(const f16* __restrict__ Yl,
                                               const f16* __restrict__ Yr,
                                               const int* __restrict__ rowptr,
                                               const int* __restrict__ s_src,
                                               const float* __restrict__ s_ew,
                                               const float* __restrict__ bias,
                                               f16* __restrict__ z) {
  int node = blockIdx.x;
  int w = threadIdx.x >> 6, lane = threadIdx.x & 63;
  int beg = rowptr[node], end = rowptr[node + 1];
  float a0[8] = {0, 0, 0, 0, 0, 0, 0, 0};
  float a1[8] = {0, 0, 0, 0, 0, 0, 0, 0};
  int k = beg + w;
  for (; k + 4 < end; k += 8) {
    int sA = s_src[k], sB = s_src[k + 4];
    float wA = s_ew[k], wB = s_ew[k + 4];
    f16x8 vA = *(const f16x8*)(Yl + (size_t)sA * 512 + lane * 8);
    f16x8 vB = *(const f16x8*)(Yl + (size_t)sB * 512 + lane * 8);
#pragma unroll
    for (int t = 0; t < 8; ++t) {
      a0[t] += (float)vA[t] * wA;
      a1[t] += (float)vB[t] * wB;
    }
  }
  if (k < end) {
    int sA = s_src[k];
    float wA = s_ew[k];
    f16x8 vA = *(const f16x8*)(Yl + (size_t)sA * 512 + lane * 8);
#pragma unroll
    for (int t = 0; t < 8; ++t) a0[t] += (float)vA[t] * wA;
  }
  __shared__ float red[4][8][64];
#pragma unroll
  for (int t = 0; t < 8; ++t) red[w][t][lane] = a0[t] + a1[t];
  __syncthreads();
  if (w == 0) {
    float inv = 1.0f / fmaxf((float)(end - beg), 1.0f);
    f16x8 rt = *(const f16x8*)(Yr + (size_t)node * 512 + lane * 8);
    float4 b0 = *(const float4*)(bias + lane * 8);
    float4 b1v = *(const float4*)(bias + lane * 8 + 4);
    float bb[8] = {b0.x, b0.y, b0.z, b0.w, b1v.x, b1v.y, b1v.z, b1v.w};
    f16x8 o;
#pragma unroll
    for (int t = 0; t < 8; ++t) {
      float s = red[0][t][lane] + red[1][t][lane] + red[2][t][lane] + red[3][t][lane];
      float v = s * inv + (float)rt[t] + bb[t];
      v = fmaxf(v, 0.0f);
      o[t] = (f16)v;
    }
    *(f16x8*)(z + (size_t)node * DIM + lane * 8) = o;
  }
}

// ---------------- combine_dec: AB = mean-gather(Ql) + Qr -----------------------
// One block (4 waves) per node; 64 lanes x f16x2 = 128 cols; LDS [4][2][64] reduce.

__global__ __launch_bounds__(256) void combine_dec(const f16* __restrict__ Ql,
                                                   const f16* __restrict__ Qr,
                                                   const int* __restrict__ rowptr,
                                                   const int* __restrict__ s_src,
                                                   const float* __restrict__ s_ew,
                                                   f16* __restrict__ AB) {
  int node = blockIdx.x;
  int w = threadIdx.x >> 6, lane = threadIdx.x & 63;
  int col = lane * 2;
  int beg = rowptr[node], end = rowptr[node + 1];
  float p0 = 0, p1 = 0, q0 = 0, q1 = 0;
  int k = beg + w;
  for (; k + 4 < end; k += 8) {
    int sA = s_src[k], sB = s_src[k + 4];
    float wA = s_ew[k], wB = s_ew[k + 4];
    f16x2 vA = *(const f16x2*)(Ql + (size_t)sA * 128 + col);
    f16x2 vB = *(const f16x2*)(Ql + (size_t)sB * 128 + col);
    p0 += (float)vA[0] * wA; p1 += (float)vA[1] * wA;
    q0 += (float)vB[0] * wB; q1 += (float)vB[1] * wB;
  }
  if (k < end) {
    int sA = s_src[k];
    float wA = s_ew[k];
    f16x2 vA = *(const f16x2*)(Ql + (size_t)sA * 128 + col);
    p0 += (float)vA[0] * wA; p1 += (float)vA[1] * wA;
  }
  __shared__ float red[4][2][64];
  red[w][0][lane] = p0 + q0;
  red[w][1][lane] = p1 + q1;
  __syncthreads();
  if (w == 0) {
    float inv = 1.0f / fmaxf((float)(end - beg), 1.0f);
    f16x2 rt = *(const f16x2*)(Qr + (size_t)node * 128 + col);
    float s0 = red[0][0][lane] + red[1][0][lane] + red[2][0][lane] + red[3][0][lane];
    float s1 = red[0][1][lane] + red[1][1][lane] + red[2][1][lane] + red[3][1][lane];
    f16x2 o = {(f16)(s0 * inv + (float)rt[0]), (f16)(s1 * inv + (float)rt[1])};
    *(f16x2*)(AB + (size_t)node * 128 + col) = o;
  }
}

// ---------------- edge decoder: half-wave (32 lanes) per edge, f16x2 loads --------

__global__ __launch_bounds__(256) void decode_kernel(const f16* __restrict__ AB,
                                                     const int* __restrict__ eli,
                                                     const float* __restrict__ expw,
                                                     const float* __restrict__ wrow,
                                                     const float* __restrict__ dvec,
                                                     const float* __restrict__ Wd2,
                                                     const float* __restrict__ bd2,
                                                     float* __restrict__ out, int E) {
  int wid = blockIdx.x * 8 + (threadIdx.x >> 5);
  int j = threadIdx.x & 31;
  if (wid >= E) return;
  int s = eli[wid];
  int d = eli[E + wid];
  float2 sw = *(const float2*)(wrow + 2 * j);
  float2 sb = *(const float2*)(dvec + 2 * j);
  float2 s2 = *(const float2*)(Wd2 + 2 * j);
  f16x2 va = *(const f16x2*)(AB + (size_t)s * 128 + 2 * j);
  f16x2 vb = *(const f16x2*)(AB + (size_t)d * 128 + 64 + 2 * j);
  float w = expw[wid];
  float h0 = fmaxf((float)va[0] + (float)vb[0] + w * sw.x + sb.x, 0.0f);
  float h1 = fmaxf((float)va[1] + (float)vb[1] + w * sw.y + sb.y, 0.0f);
  float p = h0 * s2.x + h1 * s2.y;
#pragma unroll
  for (int off = 16; off >= 1; off >>= 1) p += __shfl_xor(p, off);
  if (j == 0) out[wid] = p + bd2[0];
}

// ---------------- launcher ----------------

extern "C" void kernel_launch(void* const* d_in, const int* in_sizes, int n_in,
                              void* d_out, int out_size, void* d_ws, size_t ws_size,
                              hipStream_t stream) {
  const float* x    = (const float*)d_in[0];
  const float* ew   = (const float*)d_in[1];
  const float* expw = (const float*)d_in[2];
  const float* W1r  = (const float*)d_in[3];
  const float* b1   = (const float*)d_in[4];
  const float* W1o  = (const float*)d_in[5];
  const float* W2r  = (const float*)d_in[6];
  const float* b2   = (const float*)d_in[7];
  const float* W2o  = (const float*)d_in[8];
  const float* Wd1  = (const float*)d_in[9];
  const float* bd1  = (const float*)d_in[10];
  const float* Wd2  = (const float*)d_in[11];
  const float* bd2  = (const float*)d_in[12];
  const int* ei     = (const int*)d_in[13];
  const int* eli    = (const int*)d_in[14];
  float* out = (float*)d_out;

  char* ws = (char*)d_ws;
  int* deg    = (int*)(ws + 0);
  int* rowptr = (int*)(ws + 40064);
  int* cursor = (int*)(ws + 80128);
  int* s_src  = (int*)(ws + 120192);
  float* s_ew = (float*)(ws + 760192);
  f16* x16    = (f16*)(ws + 1400192);   // 10.24 MB
  f16* z1     = (f16*)(ws + 11640192);  // 10.24 MB
  f16* Yl     = (f16*)(ws + 21880192);  // 10.24 MB
  f16* Yr     = (f16*)(ws + 32120192);  // 10.24 MB
  f16* Ql     = (f16*)(ws + 42360192);  // 2.56 MB [10000][128]
  f16* Qr     = (f16*)(ws + 44920192);  // 2.56 MB
  f16* AB16   = (f16*)(ws + 47480192);  // 2.56 MB
  f16* w1c    = (f16*)(ws + 50040192);  // 1 MB  [1024][512] transposed W1r|W1o
  f16* w2cat  = (f16*)(ws + 51088768);  // 1 MB  [1024][512] row-major W2r;W2o (cast)
  f16* bdt    = (f16*)(ws + 52137344);  // 128 KB [128][512] Wdc^T
  f16* cwt    = (f16*)(ws + 52268416);  // 256 KB [256][512]: (W2r@Wdc)^T ; (W2o@Wdc)^T
  float* dvec = (float*)(ws + 52530560);  // 256 B

  const int* src = ei;
  const int* dst = ei + NE;

  // fused setup: zero deg, cast x, cast W2, build bdt, dvec, transpose W1
  setup_kernel<<<6000, 256, 0, stream>>>(x, x16, deg, W1r, W1o, W2r, W2o, Wd1, b2, bd1,
                                         w1c, w2cat, bdt, dvec);

  // CSR
  hist_kernel<<<625, 256, 0, stream>>>(dst, deg, NE);
  scan_kernel<<<1, 256, 0, stream>>>(deg, rowptr, cursor);
  scatter_kernel<<<625, 256, 0, stream>>>(src, dst, ew, cursor, s_src, s_ew, NE);

  // layer 1 GEMM (blocks 0-631) + weight-fold GEMM (blocks 632-639) in one launch:
  //   [Yl|Yr] = x @ [W1r | W1o]           (632 blocks)
  //   cwt = bdt @ w2cat^T  -> (W2r@Wdc)^T rows 0-127, (W2o@Wdc)^T rows 128-255 (8 blocks)
  gemm_f16<128, 128><<<640, 256, 0, stream>>>(x16, w1c, Yl, Yr, N_NODES, 8, 512, 512,
                                              632, bdt, w2cat, cwt, cwt + 128 * 512,
                                              128, 8, 512, 512);

  // z1 = relu(mean-agg(Yl) + Yr + b1)   (one block per node, tail-balanced)
  combine<<<N_NODES, 256, 0, stream>>>(Yl, Yr, rowptr, s_src, s_ew, b1, z1);

  // fused layer-2 + decoder projection: [Ql|Qr] = z1 @ [CWrel | CWroot]
  gemm_f16<64, 64><<<628, 256, 0, stream>>>(z1, cwt, Ql, Qr, N_NODES, 4, 128, 128, 628,
                                            nullptr, nullptr, nullptr, nullptr, 0, 1, 0,
                                            128);

  // AB = mean-agg(Ql) + Qr   (one block per node)
  combine_dec<<<N_NODES, 256, 0, stream>>>(Ql, Qr, rowptr, s_src, s_ew, AB16);

  // per-edge decode (dvec folds bd1 + b2@Wdc)
  decode_kernel<<<20000, 256, 0, stream>>>(AB16, eli, expw, Wd1 + 1024 * 64, dvec, Wd2,
                                           bd2, out, NE);
}

// Round 13
// 95.777 us; speedup vs baseline: 1.5302x; 1.5302x over previous
//
#include <hip/hip_runtime.h>

#define N_NODES 10000
#define DIM 512
#define NE 160000

typedef _Float16 f16;
typedef _Float16 f16x2 __attribute__((ext_vector_type(2)));
typedef _Float16 f16x8 __attribute__((ext_vector_type(8)));
typedef float f32x4 __attribute__((ext_vector_type(4)));

__device__ __forceinline__ void gload16(const void* g, void* l) {
  __builtin_amdgcn_global_load_lds((const __attribute__((address_space(1))) void*)g,
                                   (__attribute__((address_space(3))) void*)l, 16, 0, 0);
}

// ---------------- fused setup: zero cnt + cast x + all weight prep ----------------
// blocks [0,40):        zero cnt
// blocks [40,5040):     cast x -> x16
// blocks [5040,5552):   cast W2r/W2o -> w2cat
// blocks [5552,5808):   wd1_build -> bdt
// blocks [5808,5872):   dvec
// blocks [5872,6000):   wtrans W1r/W1o -> w1c

__global__ __launch_bounds__(256) void setup_kernel(
    const float* __restrict__ x, f16* __restrict__ x16, int* __restrict__ cnt,
    const float* __restrict__ W1r, const float* __restrict__ W1o,
    const float* __restrict__ W2r, const float* __restrict__ W2o,
    const float* __restrict__ Wd1, const float* __restrict__ b2,
    const float* __restrict__ bd1, f16* __restrict__ w1c, f16* __restrict__ w2cat,
    f16* __restrict__ bdt, float* __restrict__ dvec) {
  int b = blockIdx.x, t = threadIdx.x;
  if (b < 40) {
    int i = b * 256 + t;
    if (i < N_NODES) cnt[i] = 0;
    return;
  }
  b -= 40;
  if (b < 5000) {  // cast x
    int i = b * 256 + t;
    float4 v = ((const float4*)x)[i];
    f16 h0 = (f16)v.x, h1 = (f16)v.y, h2 = (f16)v.z, h3 = (f16)v.w;
    ushort4 hv = {*(ushort*)&h0, *(ushort*)&h1, *(ushort*)&h2, *(ushort*)&h3};
    ((ushort4*)x16)[i] = hv;
    return;
  }
  b -= 5000;
  if (b < 512) {  // cast W2r / W2o
    const float* s = (b < 256) ? W2r : W2o;
    f16* d = w2cat + (b < 256 ? 0 : (size_t)512 * 512);
    int i = (b & 255) * 256 + t;
    float4 v = ((const float4*)s)[i];
    f16 h0 = (f16)v.x, h1 = (f16)v.y, h2 = (f16)v.z, h3 = (f16)v.w;
    ushort4 hv = {*(ushort*)&h0, *(ushort*)&h1, *(ushort*)&h2, *(ushort*)&h3};
    ((ushort4*)d)[i] = hv;
    return;
  }
  b -= 512;
  if (b < 256) {  // wd1_build: bdt[j][k] = Wd1[(j<64?k:512+k)][j&63]
    int lin = b * 256 + t;
    int j = lin >> 9, k = lin & 511;
    bdt[lin] = (f16)Wd1[(size_t)(j < 64 ? k : 512 + k) * 64 + (j & 63)];
    return;
  }
  b -= 256;
  if (b < 64) {  // dvec[j] = bd1[j] + sum_k b2[k]*(Wd1[k][j]+Wd1[512+k][j])
    int j = b;
    float s = 0;
    for (int k = t; k < 512; k += 256) {
      float bk = b2[k];
      s += bk * (Wd1[(size_t)k * 64 + j] + Wd1[(size_t)(512 + k) * 64 + j]);
    }
#pragma unroll
    for (int off = 32; off >= 1; off >>= 1) s += __shfl_xor(s, off);
    __shared__ float red[4];
    int w = t >> 6, l = t & 63;
    if (l == 0) red[w] = s;
    __syncthreads();
    if (t == 0) dvec[j] = bd1[j] + red[0] + red[1] + red[2] + red[3];
    return;
  }
  b -= 64;
  {  // wtrans: W1r (b<64) / W1o (b>=64) -> w1c transposed fp16
    const float* src = (b < 64) ? W1r : W1o;
    f16* dh = w1c + (b < 64 ? 0 : (size_t)512 * 512);
    int tile = b & 63;
    __shared__ float sT[64][65];
    int tr = tile >> 3, tc = tile & 7;
    for (int i = 0; i < 16; ++i) {
      int lin = i * 256 + t;
      int r = lin >> 6, c = lin & 63;
      sT[r][c] = src[(size_t)(tr * 64 + r) * 512 + tc * 64 + c];
    }
    __syncthreads();
    for (int i = 0; i < 16; ++i) {
      int lin = i * 256 + t;
      int n = lin >> 6, k = lin & 63;
      dh[(size_t)(tc * 64 + n) * 512 + tr * 64 + k] = (f16)sT[k][n];
    }
  }
}

// ---------------- MFMA GEMM (dual-problem + ELL-scatter segment) -----------------
// Blocks [0,n1): problem 1. [n1,n1+n2): problem 2. [n1+n2,grid): ELL edge scatter
// (independent work riding in the same launch; cnt must be pre-zeroed).
// GEMM: A [M][512] fp16, B [NB*BN][512] fp16, tile BM x BN, 4 waves 2x2, BK=32,
// K=512. Columns >= nsplit go to outB at (col-nsplit); stride ldo.
// XCD-chunked bijective block swizzle per segment (T1/m204).

template <int BM, int BN>
__global__ __launch_bounds__(256) void gemm_f16(
    const f16* __restrict__ A1, const f16* __restrict__ B1, f16* __restrict__ oA1,
    f16* __restrict__ oB1, int M1, int NB1, int ns1, int ldo1, int n1,
    const f16* __restrict__ A2, const f16* __restrict__ B2, f16* __restrict__ oA2,
    f16* __restrict__ oB2, int M2, int NB2, int ns2, int ldo2, int n2,
    const int* __restrict__ g_src, const int* __restrict__ g_dst,
    const float* __restrict__ g_ew, int* __restrict__ cnt, int* __restrict__ e_src,
    float* __restrict__ e_ew, int nedge) {
  constexpr int ASLOTS = BM / 16;
  constexpr int SLOTS = (BM + BN) / 16;
  constexpr int SPW = SLOTS / 4;
  constexpr int MI = BM / 32;
  constexpr int NJ = BN / 32;
  __shared__ char smem[SLOTS * 1024];

  int lin = blockIdx.x;
  if (lin >= n1 + n2) {  // ELL scatter segment
    int e = (lin - n1 - n2) * 256 + threadIdx.x;
    if (e < nedge) {
      int d = g_dst[e];
      int p = atomicAdd(&cnt[d], 1);
      if (p < 64) {
        e_src[(d << 6) + p] = g_src[e];
        e_ew[(d << 6) + p] = g_ew[e];
      }
    }
    return;
  }

  const f16 *A, *B;
  f16 *outA, *outB;
  int M, NB, nsplit, ldo, n;
  if (lin < n1) {
    A = A1; B = B1; outA = oA1; outB = oB1;
    M = M1; NB = NB1; nsplit = ns1; ldo = ldo1; n = n1;
  } else {
    lin -= n1;
    A = A2; B = B2; outA = oA2; outB = oB2;
    M = M2; NB = NB2; nsplit = ns2; ldo = ldo2; n = n2;
  }

  // bijective XCD swizzle within segment; bn varies fastest
  int q = n >> 3, r = n & 7, xcd = lin & 7;
  int base = xcd < r ? xcd * (q + 1) : r * (q + 1) + (xcd - r) * q;
  int swz = base + (lin >> 3);
  int bm = (swz / NB) * BM;
  int bn = (swz % NB) * BN;

  int tid = threadIdx.x;
  int w = tid >> 6, l = tid & 63;
  int wr = w & 1, wc = w >> 1;

  f32x4 acc[MI][NJ] = {};

  int lr = l >> 2;        // row within 16-row slot
  int lc = (l & 3) * 8;   // fp16 offset within 32-wide stripe

  for (int k0 = 0; k0 < 512; k0 += 32) {
    __syncthreads();
#pragma unroll
    for (int i = 0; i < SPW; ++i) {
      int s = w * SPW + i;
      const f16* src;
      int grow;
      if (s < ASLOTS) {
        src = A; grow = bm + s * 16 + lr; if (grow > M - 1) grow = M - 1;
      } else {
        src = B; grow = bn + (s - ASLOTS) * 16 + lr;
      }
      gload16(src + (size_t)grow * 512 + k0 + lc, smem + s * 1024);
    }
    __syncthreads();

    int rsel = l & 15;
    int ksb = (l >> 4) * 16;  // byte offset of k-slice
    f16x8 fA[MI], fB[NJ];
#pragma unroll
    for (int i = 0; i < MI; ++i) {
      int ra = wr * (BM / 2) + i * 16 + rsel;
      fA[i] = *(const f16x8*)(smem + ra * 64 + ksb);
    }
#pragma unroll
    for (int j = 0; j < NJ; ++j) {
      int rb = wc * (BN / 2) + j * 16 + rsel;
      fB[j] = *(const f16x8*)(smem + ASLOTS * 1024 + rb * 64 + ksb);
    }
#pragma unroll
    for (int i = 0; i < MI; ++i)
#pragma unroll
      for (int j = 0; j < NJ; ++j)
        acc[i][j] = __builtin_amdgcn_mfma_f32_16x16x32_f16(fA[i], fB[j], acc[i][j], 0, 0, 0);
  }

  // epilogue: C/D layout col = lane&15, row = (lane>>4)*4 + reg
#pragma unroll
  for (int i = 0; i < MI; ++i) {
#pragma unroll
    for (int j = 0; j < NJ; ++j) {
      int col = bn + wc * (BN / 2) + j * 16 + (l & 15);
      f16* outp; int ocol;
      if (col < nsplit) { outp = outA; ocol = col; }
      else              { outp = outB; ocol = col - nsplit; }
#pragma unroll
      for (int rg = 0; rg < 4; ++rg) {
        int row = bm + wr * (BM / 2) + i * 16 + (l >> 4) * 4 + rg;
        if (row < M) outp[(size_t)row * ldo + ocol] = (f16)acc[i][j][rg];
      }
    }
  }
}

// ---------------- combine: z = relu(mean-gather(Yl) + Yr + bias) --------
// ELL lists: e_src/e_ew [node][64], deg = min(cnt,64). One wave per node,
// f16x8 loads, 4-deep unroll.

__global__ __launch_bounds__(256) void combine(const f16* __restrict__ Yl,
                                               const f16* __restrict__ Yr,
                                               const int* __restrict__ cnt,
                                               const int* __restrict__ e_src,
                                               const float* __restrict__ e_ew,
                                               const float* __restrict__ bias,
                                               f16* __restrict__ z) {
  int wid = (blockIdx.x * blockDim.x + threadIdx.x) >> 6;
  int lane = threadIdx.x & 63;
  if (wid >= N_NODES) return;
  int deg = min(cnt[wid], 64);
  int basei = wid << 6;
  float a0[8] = {0, 0, 0, 0, 0, 0, 0, 0};
  float a1[8] = {0, 0, 0, 0, 0, 0, 0, 0};
  int k = 0;
  for (; k + 3 < deg; k += 4) {
    int sA = e_src[basei + k], sB = e_src[basei + k + 1];
    int sC = e_src[basei + k + 2], sD = e_src[basei + k + 3];
    float wA = e_ew[basei + k], wB = e_ew[basei + k + 1];
    float wC = e_ew[basei + k + 2], wD = e_ew[basei + k + 3];
    f16x8 vA = *(const f16x8*)(Yl + (size_t)sA * 512 + lane * 8);
    f16x8 vB = *(const f16x8*)(Yl + (size_t)sB * 512 + lane * 8);
    f16x8 vC = *(const f16x8*)(Yl + (size_t)sC * 512 + lane * 8);
    f16x8 vD = *(const f16x8*)(Yl + (size_t)sD * 512 + lane * 8);
#pragma unroll
    for (int t = 0; t < 8; ++t) {
      a0[t] += (float)vA[t] * wA + (float)vC[t] * wC;
      a1[t] += (float)vB[t] * wB + (float)vD[t] * wD;
    }
  }
  for (; k < deg; ++k) {
    int sA = e_src[basei + k];
    float wA = e_ew[basei + k];
    f16x8 vA = *(const f16x8*)(Yl + (size_t)sA * 512 + lane * 8);
#pragma unroll
    for (int t = 0; t < 8; ++t) a0[t] += (float)vA[t] * wA;
  }
  float inv = 1.0f / fmaxf((float)deg, 1.0f);
  f16x8 rt = *(const f16x8*)(Yr + (size_t)wid * 512 + lane * 8);
  float4 b0 = *(const float4*)(bias + lane * 8);
  float4 b1v = *(const float4*)(bias + lane * 8 + 4);
  float bb[8] = {b0.x, b0.y, b0.z, b0.w, b1v.x, b1v.y, b1v.z, b1v.w};
  f16x8 o;
#pragma unroll
  for (int t = 0; t < 8; ++t) {
    float v = (a0[t] + a1[t]) * inv + (float)rt[t] + bb[t];
    v = fmaxf(v, 0.0f);
    o[t] = (f16)v;
  }
  *(f16x8*)(z + (size_t)wid * DIM + lane * 8) = o;
}

// ---------------- combine_dec: AB = mean-gather(Ql) + Qr -----------------------
// ELL lists; one wave per node, 64 lanes x f16x2 (256 B rows).

__global__ __launch_bounds__(256) void combine_dec(const f16* __restrict__ Ql,
                                                   const f16* __restrict__ Qr,
                                                   const int* __restrict__ cnt,
                                                   const int* __restrict__ e_src,
                                                   const float* __restrict__ e_ew,
                                                   f16* __restrict__ AB) {
  int wid = (blockIdx.x * blockDim.x + threadIdx.x) >> 6;
  int lane = threadIdx.x & 63;
  if (wid >= N_NODES) return;
  int deg = min(cnt[wid], 64);
  int basei = wid << 6;
  int col = lane * 2;
  float aA0 = 0, aA1 = 0, aB0 = 0, aB1 = 0, aC0 = 0, aC1 = 0, aD0 = 0, aD1 = 0;
  int k = 0;
  for (; k + 3 < deg; k += 4) {
    int sA = e_src[basei + k], sB = e_src[basei + k + 1];
    int sC = e_src[basei + k + 2], sD = e_src[basei + k + 3];
    float wA = e_ew[basei + k], wB = e_ew[basei + k + 1];
    float wC = e_ew[basei + k + 2], wD = e_ew[basei + k + 3];
    f16x2 vA = *(const f16x2*)(Ql + (size_t)sA * 128 + col);
    f16x2 vB = *(const f16x2*)(Ql + (size_t)sB * 128 + col);
    f16x2 vC = *(const f16x2*)(Ql + (size_t)sC * 128 + col);
    f16x2 vD = *(const f16x2*)(Ql + (size_t)sD * 128 + col);
    aA0 += (float)vA[0] * wA; aA1 += (float)vA[1] * wA;
    aB0 += (float)vB[0] * wB; aB1 += (float)vB[1] * wB;
    aC0 += (float)vC[0] * wC; aC1 += (float)vC[1] * wC;
    aD0 += (float)vD[0] * wD; aD1 += (float)vD[1] * wD;
  }
  for (; k < deg; ++k) {
    int sA = e_src[basei + k];
    float wA = e_ew[basei + k];
    f16x2 vA = *(const f16x2*)(Ql + (size_t)sA * 128 + col);
    aA0 += (float)vA[0] * wA; aA1 += (float)vA[1] * wA;
  }
  float inv = 1.0f / fmaxf((float)deg, 1.0f);
  f16x2 rt = *(const f16x2*)(Qr + (size_t)wid * 128 + col);
  f16x2 o = {(f16)((aA0 + aB0 + aC0 + aD0) * inv + (float)rt[0]),
             (f16)((aA1 + aB1 + aC1 + aD1) * inv + (float)rt[1])};
  *(f16x2*)(AB + (size_t)wid * 128 + col) = o;
}

// ---------------- edge decoder: half-wave (32 lanes) per edge, f16x2 loads --------

__global__ __launch_bounds__(256) void decode_kernel(const f16* __restrict__ AB,
                                                     const int* __restrict__ eli,
                                                     const float* __restrict__ expw,
                                                     const float* __restrict__ wrow,
                                                     const float* __restrict__ dvec,
                                                     const float* __restrict__ Wd2,
                                                     const float* __restrict__ bd2,
                                                     float* __restrict__ out, int E) {
  int wid = blockIdx.x * 8 + (threadIdx.x >> 5);
  int j = threadIdx.x & 31;
  if (wid >= E) return;
  int s = eli[wid];
  int d = eli[E + wid];
  float2 sw = *(const float2*)(wrow + 2 * j);
  float2 sb = *(const float2*)(dvec + 2 * j);
  float2 s2 = *(const float2*)(Wd2 + 2 * j);
  f16x2 va = *(const f16x2*)(AB + (size_t)s * 128 + 2 * j);
  f16x2 vb = *(const f16x2*)(AB + (size_t)d * 128 + 64 + 2 * j);
  float w = expw[wid];
  float h0 = fmaxf((float)va[0] + (float)vb[0] + w * sw.x + sb.x, 0.0f);
  float h1 = fmaxf((float)va[1] + (float)vb[1] + w * sw.y + sb.y, 0.0f);
  float p = h0 * s2.x + h1 * s2.y;
#pragma unroll
  for (int off = 16; off >= 1; off >>= 1) p += __shfl_xor(p, off);
  if (j == 0) out[wid] = p + bd2[0];
}

// ---------------- launcher ----------------

extern "C" void kernel_launch(void* const* d_in, const int* in_sizes, int n_in,
                              void* d_out, int out_size, void* d_ws, size_t ws_size,
                              hipStream_t stream) {
  const float* x    = (const float*)d_in[0];
  const float* ew   = (const float*)d_in[1];
  const float* expw = (const float*)d_in[2];
  const float* W1r  = (const float*)d_in[3];
  const float* b1   = (const float*)d_in[4];
  const float* W1o  = (const float*)d_in[5];
  const float* W2r  = (const float*)d_in[6];
  const float* b2   = (const float*)d_in[7];
  const float* W2o  = (const float*)d_in[8];
  const float* Wd1  = (const float*)d_in[9];
  const float* bd1  = (const float*)d_in[10];
  const float* Wd2  = (const float*)d_in[11];
  const float* bd2  = (const float*)d_in[12];
  const int* ei     = (const int*)d_in[13];
  const int* eli    = (const int*)d_in[14];
  float* out = (float*)d_out;

  char* ws = (char*)d_ws;
  int* cnt    = (int*)(ws + 0);            // 40 KB
  int* e_src  = (int*)(ws + 40064);        // 2.56 MB [10000][64]
  float* e_ew = (float*)(ws + 2600128);    // 2.56 MB
  f16* x16    = (f16*)(ws + 5160192);      // 10.24 MB
  f16* z1     = (f16*)(ws + 15400192);     // 10.24 MB
  f16* Yl     = (f16*)(ws + 25640192);     // 10.24 MB
  f16* Yr     = (f16*)(ws + 35880192);     // 10.24 MB
  f16* Ql     = (f16*)(ws + 46120192);     // 2.56 MB [10000][128]
  f16* Qr     = (f16*)(ws + 48680192);     // 2.56 MB
  f16* AB16   = (f16*)(ws + 51240192);     // 2.56 MB
  f16* w1c    = (f16*)(ws + 53800192);     // 1 MB [1024][512] transposed W1r|W1o
  f16* w2cat  = (f16*)(ws + 54848768);     // 1 MB [1024][512] row-major W2r;W2o
  f16* bdt    = (f16*)(ws + 55897344);     // 128 KB [128][512] Wdc^T
  f16* cwt    = (f16*)(ws + 56028416);     // 256 KB [256][512]
  float* dvec = (float*)(ws + 56290560);   // 256 B

  const int* src = ei;
  const int* dst = ei + NE;

  // 1) fused setup: zero cnt, cast x, cast W2, build bdt, dvec, transpose W1
  setup_kernel<<<6000, 256, 0, stream>>>(x, x16, cnt, W1r, W1o, W2r, W2o, Wd1, b2, bd1,
                                         w1c, w2cat, bdt, dvec);

  // 2) layer-1 GEMM (632) + weight-fold GEMM (8) + ELL edge scatter (625), one launch
  gemm_f16<128, 128><<<1265, 256, 0, stream>>>(
      x16, w1c, Yl, Yr, N_NODES, 8, 512, 512, 632,
      bdt, w2cat, cwt, cwt + 128 * 512, 128, 8, 512, 512, 8,
      src, dst, ew, cnt, e_src, e_ew, NE);

  // 3) z1 = relu(mean-agg(Yl) + Yr + b1)
  combine<<<2500, 256, 0, stream>>>(Yl, Yr, cnt, e_src, e_ew, b1, z1);

  // 4) fused layer-2 + decoder projection: [Ql|Qr] = z1 @ [CWrel | CWroot]
  gemm_f16<64, 64><<<628, 256, 0, stream>>>(
      z1, cwt, Ql, Qr, N_NODES, 4, 128, 128, 628,
      nullptr, nullptr, nullptr, nullptr, 0, 1, 0, 128, 0,
      nullptr, nullptr, nullptr, nullptr, nullptr, nullptr, 0);

  // 5) AB = mean-agg(Ql) + Qr
  combine_dec<<<2500, 256, 0, stream>>>(Ql, Qr, cnt, e_src, e_ew, AB16);

  // 6) per-edge decode (dvec folds bd1 + b2@Wdc)
  decode_kernel<<<20000, 256, 0, stream>>>(AB16, eli, expw, Wd1 + 1024 * 64, dvec, Wd2,
                                           bd2, out, NE);
}